// Round 10
// baseline (342.011 us; speedup 1.0000x reference)
//
#include <hip/hip_runtime.h>
#include <cstddef>

// Problem constants
#define B_   4
#define NS_  96
#define T_   8
#define H_   256
#define N_   97      // NS + 1
#define NL_  6       // NUM_LAYERS
#define R_   388     // B_ * N_

// fast gates: v_exp_f32 (2^x) + v_rcp_f32
__device__ __forceinline__ float sigm(float x) {
    return __builtin_amdgcn_rcpf(1.0f + __builtin_amdgcn_exp2f(-1.44269504f * x));
}
__device__ __forceinline__ float tanh_f(float x) {
    return 1.0f - 2.0f * __builtin_amdgcn_rcpf(1.0f + __builtin_amdgcn_exp2f(2.88539008f * x));
}

__device__ __forceinline__ void fma16(float4 a, float4 w0, float4 w1, float4 w2,
                                      float4 w3, float* acc) {
    acc[0] = fmaf(a.x, w0.x, acc[0]); acc[1] = fmaf(a.x, w0.y, acc[1]);
    acc[2] = fmaf(a.x, w0.z, acc[2]); acc[3] = fmaf(a.x, w0.w, acc[3]);
    acc[0] = fmaf(a.y, w1.x, acc[0]); acc[1] = fmaf(a.y, w1.y, acc[1]);
    acc[2] = fmaf(a.y, w1.z, acc[2]); acc[3] = fmaf(a.y, w1.w, acc[3]);
    acc[0] = fmaf(a.z, w2.x, acc[0]); acc[1] = fmaf(a.z, w2.y, acc[1]);
    acc[2] = fmaf(a.z, w2.z, acc[2]); acc[3] = fmaf(a.z, w2.w, acc[3]);
    acc[0] = fmaf(a.w, w3.x, acc[0]); acc[1] = fmaf(a.w, w3.y, acc[1]);
    acc[2] = fmaf(a.w, w3.z, acc[2]); acc[3] = fmaf(a.w, w3.w, acc[3]);
}

// ============ prologue: 512-thr blocks ============
// 0..383: xz tiles; 384..415: M1 = W_se@Wx_e; 416..423: M2 = W_se@W_sd;
// 424..425: cz; 426..427: hw; 428: ck.  Small sections use 4-acc pipelined k-loops.
__global__ __launch_bounds__(512, 4) void prologue(
        const int* __restrict__ ids, const float* __restrict__ embed,
        const float* __restrict__ Wx_s, const float* __restrict__ b_s,
        const float* __restrict__ b_se, const float* __restrict__ Wx_e,
        const float* __restrict__ b_e, const float* __restrict__ W_sd,
        const float* __restrict__ b_sd, const float* __restrict__ Wh_e,
        const float* __restrict__ W_se, const float* __restrict__ init_b,
        float* __restrict__ xz, float* __restrict__ cz, float* __restrict__ ck,
        float* __restrict__ hw, float* __restrict__ Mbuf) {
    int bid = blockIdx.x, t = threadIdx.x;
    if (bid < 384) {                      // xz = embed[ids] @ Wx_s + b_s, 64x128 tile
        __shared__ float As[64][260];
        __shared__ int ridx[64];
        int r0 = (bid >> 3) * 64, n0 = (bid & 7) * 128;
        if (t < 64) ridx[t] = ids[r0 + t];
        __syncthreads();
#pragma unroll
        for (int m = 0; m < 8; m++) {     // stage 64x256 (8 float4/thread)
            int L = m * 512 + t;
            int r = L >> 6, c4 = (L & 63) * 4;
            *(float4*)&As[r][c4] = *(const float4*)(embed + (size_t)ridx[r] * 256 + c4);
        }
        __syncthreads();
        int rg = t >> 5, cg = t & 31;     // 16 row-groups x 32 col-quads
        float acc[4][4] = {};
        const float* wp = Wx_s + n0 + 4 * cg;
#pragma unroll 4
        for (int kb = 0; kb < 64; kb++) {
            float4 w0 = *(const float4*)(wp + (size_t)(4 * kb + 0) * 1024);
            float4 w1 = *(const float4*)(wp + (size_t)(4 * kb + 1) * 1024);
            float4 w2 = *(const float4*)(wp + (size_t)(4 * kb + 2) * 1024);
            float4 w3 = *(const float4*)(wp + (size_t)(4 * kb + 3) * 1024);
#pragma unroll
            for (int i = 0; i < 4; i++) {
                float4 a = *(const float4*)&As[rg * 4 + i][4 * kb];
                fma16(a, w0, w1, w2, w3, acc[i]);
            }
        }
        int col = n0 + 4 * cg;
        float4 bv = *(const float4*)&b_s[col];
#pragma unroll
        for (int i = 0; i < 4; i++) {
            int r = r0 + rg * 4 + i;
            float4 o = make_float4(acc[i][0] + bv.x, acc[i][1] + bv.y,
                                   acc[i][2] + bv.z, acc[i][3] + bv.w);
            *(float4*)&xz[(size_t)r * 1024 + col] = o;
        }
    } else if (bid < 424) {               // M1 (32 blocks) / M2 (8 blocks)
        __shared__ float As[64][260];
        bool isM1 = bid < 416;
        int mb = isM1 ? bid - 384 : bid - 416;
        int r0m = isM1 ? (mb >> 3) * 64 : (mb >> 1) * 64;
        int n0 = isM1 ? (mb & 7) * 128 : (mb & 1) * 128;
        const float* W = isM1 ? Wx_e : W_sd;
        int NC = isM1 ? 1024 : 256;
        int cbase = isM1 ? 0 : 1024;
#pragma unroll
        for (int m = 0; m < 8; m++) {     // stage W_se rows r0m..r0m+63
            int L = m * 512 + t;
            int r = L >> 6, c4 = (L & 63) * 4;
            *(float4*)&As[r][c4] = *(const float4*)(W_se + (size_t)(r0m + r) * 256 + c4);
        }
        __syncthreads();
        int rg = t >> 5, cg = t & 31;
        float acc[4][4] = {};
        const float* wp = W + n0 + 4 * cg;
#pragma unroll 4
        for (int kb = 0; kb < 64; kb++) {
            float4 w0 = *(const float4*)(wp + (size_t)(4 * kb + 0) * NC);
            float4 w1 = *(const float4*)(wp + (size_t)(4 * kb + 1) * NC);
            float4 w2 = *(const float4*)(wp + (size_t)(4 * kb + 2) * NC);
            float4 w3 = *(const float4*)(wp + (size_t)(4 * kb + 3) * NC);
#pragma unroll
            for (int i = 0; i < 4; i++) {
                float4 a = *(const float4*)&As[rg * 4 + i][4 * kb];
                fma16(a, w0, w1, w2, w3, acc[i]);
            }
        }
        int col = cbase + n0 + 4 * cg;
#pragma unroll
        for (int i = 0; i < 4; i++) {
            int r = r0m + rg * 4 + i;
            *(float4*)&Mbuf[(size_t)r * 1280 + col] =
                make_float4(acc[i][0], acc[i][1], acc[i][2], acc[i][3]);
        }
    } else if (bid < 426) {               // cz[n] = b_e + b_se@Wx_e (pipelined)
        int n = (bid - 424) * 512 + t;
        float acc[4] = {};
#pragma unroll 4
        for (int k = 0; k < 256; k += 4) {
            acc[0] = fmaf(b_se[k + 0], Wx_e[(size_t)(k + 0) * 1024 + n], acc[0]);
            acc[1] = fmaf(b_se[k + 1], Wx_e[(size_t)(k + 1) * 1024 + n], acc[1]);
            acc[2] = fmaf(b_se[k + 2], Wx_e[(size_t)(k + 2) * 1024 + n], acc[2]);
            acc[3] = fmaf(b_se[k + 3], Wx_e[(size_t)(k + 3) * 1024 + n], acc[3]);
        }
        cz[n] = b_e[n] + ((acc[0] + acc[1]) + (acc[2] + acc[3]));
    } else if (bid < 428) {               // hw[n] = cz[n] + init_b@Wh_e (pipelined)
        int n = (bid - 426) * 512 + t;
        float acc[4] = {}, bcc[4] = {};
#pragma unroll 4
        for (int k = 0; k < 256; k += 4) {
            acc[0] = fmaf(b_se[k + 0], Wx_e[(size_t)(k + 0) * 1024 + n], acc[0]);
            acc[1] = fmaf(b_se[k + 1], Wx_e[(size_t)(k + 1) * 1024 + n], acc[1]);
            acc[2] = fmaf(b_se[k + 2], Wx_e[(size_t)(k + 2) * 1024 + n], acc[2]);
            acc[3] = fmaf(b_se[k + 3], Wx_e[(size_t)(k + 3) * 1024 + n], acc[3]);
            bcc[0] = fmaf(init_b[k + 0], Wh_e[(size_t)(k + 0) * 1024 + n], bcc[0]);
            bcc[1] = fmaf(init_b[k + 1], Wh_e[(size_t)(k + 1) * 1024 + n], bcc[1]);
            bcc[2] = fmaf(init_b[k + 2], Wh_e[(size_t)(k + 2) * 1024 + n], bcc[2]);
            bcc[3] = fmaf(init_b[k + 3], Wh_e[(size_t)(k + 3) * 1024 + n], bcc[3]);
        }
        hw[n] = b_e[n] + ((acc[0] + acc[1]) + (acc[2] + acc[3]))
                       + ((bcc[0] + bcc[1]) + (bcc[2] + bcc[3]));
    } else {                              // ck (pipelined)
        if (t < 256) {
            float acc[4] = {};
#pragma unroll 4
            for (int k = 0; k < 256; k += 4) {
                acc[0] = fmaf(b_se[k + 0], W_sd[(size_t)(k + 0) * 256 + t], acc[0]);
                acc[1] = fmaf(b_se[k + 1], W_sd[(size_t)(k + 1) * 256 + t], acc[1]);
                acc[2] = fmaf(b_se[k + 2], W_sd[(size_t)(k + 2) * 256 + t], acc[2]);
                acc[3] = fmaf(b_se[k + 3], W_sd[(size_t)(k + 3) * 256 + t], acc[3]);
            }
            ck[t] = b_sd[t] + ((acc[0] + acc[1]) + (acc[2] + acc[3]));
        }
    }
}

// ============ lstm_onepass v3: all 8 steps, one launch; S=2, 192 blocks ============
__global__ __launch_bounds__(1024) void lstm_onepass(const float* __restrict__ xz,
        const float* __restrict__ Wh, float* __restrict__ hbuf) {
    __shared__ float zpart[4][2][1024];   // 32 KB
    __shared__ float h_s[2][260];         // 2 KB
    __shared__ float Wh_c[28][1024];      // 112 KB cached rows 0..27
    int t = threadIdx.x;
    int s0 = blockIdx.x * 2;
    int kg = t >> 8, tg = t & 255;
    int sg = (t >> 8) & 1, cc = t & 255;
#pragma unroll
    for (int m = 0; m < 7; m++) {
        int L = m * 1024 + t;
        int r = L >> 8, c4 = (L & 255) * 4;
        *(float4*)&Wh_c[r][c4] = *(const float4*)(Wh + (size_t)r * 1024 + c4);
    }
    float creg = 0.0f, hreg = 0.0f;
    if (t < 512) {
        const float* z0 = xz + ((size_t)(s0 + sg) * T_) * 1024;
        float gi = z0[cc], gg = z0[512 + cc], go = z0[768 + cc];
        creg = sigm(gi) * tanh_f(gg);
        hreg = sigm(go) * tanh_f(creg);
        h_s[sg][cc] = hreg;
    }
    __syncthreads();
    for (int step = 1; step < T_; step++) {
        float x0 = 0.f, x1 = 0.f, x2 = 0.f, x3 = 0.f;
        if (t < 512) {
            const float* xzp = xz + ((size_t)(s0 + sg) * T_ + step) * 1024;
            x0 = xzp[cc]; x1 = xzp[256 + cc]; x2 = xzp[512 + cc]; x3 = xzp[768 + cc];
        }
        float4 z[2] = {};
        const float* wp = Wh + (size_t)(kg * 64) * 1024 + 4 * tg;
        int kbase = kg * 64;
        if (kg == 0) {
#pragma unroll
            for (int kb = 0; kb < 7; kb++) {
                float4 w0 = *(const float4*)&Wh_c[4 * kb + 0][4 * tg];
                float4 w1 = *(const float4*)&Wh_c[4 * kb + 1][4 * tg];
                float4 w2 = *(const float4*)&Wh_c[4 * kb + 2][4 * tg];
                float4 w3 = *(const float4*)&Wh_c[4 * kb + 3][4 * tg];
                int k = 4 * kb;
#pragma unroll
                for (int s = 0; s < 2; s++) {
                    float4 a = *(const float4*)&h_s[s][k];
                    fma16(a, w0, w1, w2, w3, (float*)&z[s]);
                }
            }
#pragma unroll 3
            for (int kb = 7; kb < 16; kb++) {
                float4 w0 = *(const float4*)(wp + (size_t)(4 * kb + 0) * 1024);
                float4 w1 = *(const float4*)(wp + (size_t)(4 * kb + 1) * 1024);
                float4 w2 = *(const float4*)(wp + (size_t)(4 * kb + 2) * 1024);
                float4 w3 = *(const float4*)(wp + (size_t)(4 * kb + 3) * 1024);
                int k = 4 * kb;
#pragma unroll
                for (int s = 0; s < 2; s++) {
                    float4 a = *(const float4*)&h_s[s][k];
                    fma16(a, w0, w1, w2, w3, (float*)&z[s]);
                }
            }
        } else {
#pragma unroll 4
            for (int kb = 0; kb < 16; kb++) {
                float4 w0 = *(const float4*)(wp + (size_t)(4 * kb + 0) * 1024);
                float4 w1 = *(const float4*)(wp + (size_t)(4 * kb + 1) * 1024);
                float4 w2 = *(const float4*)(wp + (size_t)(4 * kb + 2) * 1024);
                float4 w3 = *(const float4*)(wp + (size_t)(4 * kb + 3) * 1024);
                int k = kbase + 4 * kb;
#pragma unroll
                for (int s = 0; s < 2; s++) {
                    float4 a = *(const float4*)&h_s[s][k];
                    fma16(a, w0, w1, w2, w3, (float*)&z[s]);
                }
            }
        }
#pragma unroll
        for (int s = 0; s < 2; s++)
            *(float4*)&zpart[kg][s][4 * tg] = z[s];
        __syncthreads();
        if (t < 512) {
            float zv0 = x0 + zpart[0][sg][cc] + zpart[1][sg][cc]
                      + zpart[2][sg][cc] + zpart[3][sg][cc];
            float zv1 = x1 + zpart[0][sg][256 + cc] + zpart[1][sg][256 + cc]
                      + zpart[2][sg][256 + cc] + zpart[3][sg][256 + cc];
            float zv2 = x2 + zpart[0][sg][512 + cc] + zpart[1][sg][512 + cc]
                      + zpart[2][sg][512 + cc] + zpart[3][sg][512 + cc];
            float zv3 = x3 + zpart[0][sg][768 + cc] + zpart[1][sg][768 + cc]
                      + zpart[2][sg][768 + cc] + zpart[3][sg][768 + cc];
            creg = sigm(zv1) * creg + sigm(zv0) * tanh_f(zv2);
            hreg = sigm(zv3) * tanh_f(creg);
            h_s[sg][cc] = hreg;
        }
        __syncthreads();
    }
    if (t < 512) hbuf[(size_t)(s0 + sg) * H_ + cc] = hreg;
}

// ============ templated GEMM: C = A@W, MT x 128 tile (used for y2) ============
template<int MT>
__global__ __launch_bounds__(256) void gemm_t(const float* __restrict__ A,
        const float* __restrict__ W, float* __restrict__ C, int R, int NC) {
    __shared__ float As[MT][260];
    int t = threadIdx.x;
    int n0 = blockIdx.x * 128;
    int r0 = blockIdx.y * MT;
#pragma unroll
    for (int m = 0; m < MT / 4; m++) {
        int L = m * 256 + t;
        int r = L >> 6, c4 = (L & 63) * 4;
        int rr = r0 + r;
        float4 v = make_float4(0.f, 0.f, 0.f, 0.f);
        if (rr < R) v = *(const float4*)(A + (size_t)rr * 256 + c4);
        *(float4*)&As[r][c4] = v;
    }
    __syncthreads();
    constexpr int RT = MT / 8;
    int rg = t >> 5, cg = t & 31;
    float acc[RT][4] = {};
    const float* wp = W + n0 + 4 * cg;
#pragma unroll 2
    for (int kb = 0; kb < 64; kb++) {
        float4 w0 = *(const float4*)(wp + (size_t)(4 * kb + 0) * NC);
        float4 w1 = *(const float4*)(wp + (size_t)(4 * kb + 1) * NC);
        float4 w2 = *(const float4*)(wp + (size_t)(4 * kb + 2) * NC);
        float4 w3 = *(const float4*)(wp + (size_t)(4 * kb + 3) * NC);
#pragma unroll
        for (int i = 0; i < RT; i++) {
            float4 a = *(const float4*)&As[rg * RT + i][4 * kb];
            fma16(a, w0, w1, w2, w3, acc[i]);
        }
    }
    int col = n0 + 4 * cg;
#pragma unroll
    for (int i = 0; i < RT; i++) {
        int r = r0 + rg * RT + i;
        if (r < R)
            *(float4*)&C[(size_t)r * NC + col] =
                make_float4(acc[i][0], acc[i][1], acc[i][2], acc[i][3]);
    }
}

// ============ scan_wide: per-batch column prefix scan of y2 -> q, ve0, r_, rT ============
__global__ __launch_bounds__(256) void scan_wide(const float* __restrict__ y2,
        const float* __restrict__ hw, float* __restrict__ q, float* __restrict__ ve0,
        float* __restrict__ r_, float* __restrict__ rT) {
    int bid = blockIdx.x, t = threadIdx.x;
    int b = bid / 5, ch = bid - b * 5;
    int ccol = ch * 256 + t;
    const float* yp = y2 + (size_t)b * 96 * 1280 + ccol;
    if (ccol < 1024) {
        float hwv = hw[ccol];
        float* qp = q + (size_t)b * N_ * 1024 + ccol;
        float* vp = ve0 + (size_t)b * N_ * 1024 + ccol;
        qp[0] = 0.0f; vp[0] = hwv;        // row n=0: pref = 0
        float run = 0.0f;
#pragma unroll 2
        for (int n = 1; n < N_; n += 4) {
            float v0 = yp[(size_t)(n - 1) * 1280];
            float v1 = yp[(size_t)(n + 0) * 1280];
            float v2 = yp[(size_t)(n + 1) * 1280];
            float v3 = yp[(size_t)(n + 2) * 1280];
            float rr0 = run + v0, rr1 = rr0 + v1, rr2 = rr1 + v2, rr3 = rr2 + v3;
            qp[(size_t)(n + 0) * 1024] = rr0; vp[(size_t)(n + 0) * 1024] = hwv - rr0;
            qp[(size_t)(n + 1) * 1024] = rr1; vp[(size_t)(n + 1) * 1024] = hwv - rr1;
            qp[(size_t)(n + 2) * 1024] = rr2; vp[(size_t)(n + 2) * 1024] = hwv - rr2;
            qp[(size_t)(n + 3) * 1024] = rr3; vp[(size_t)(n + 3) * 1024] = hwv - rr3;
            run = rr3;
        }
    } else {
        int rc = ccol - 1024;
        float* rp = r_ + (size_t)b * N_ * 256 + rc;
        float* rtp = rT + ((size_t)b * 256 + rc) * 128;
        rp[0] = 0.0f; rtp[0] = 0.0f;
        float run = 0.0f;
#pragma unroll 2
        for (int n = 1; n < N_; n += 4) {
            float v0 = yp[(size_t)(n - 1) * 1280];
            float v1 = yp[(size_t)(n + 0) * 1280];
            float v2 = yp[(size_t)(n + 1) * 1280];
            float v3 = yp[(size_t)(n + 2) * 1280];
            float rr0 = run + v0, rr1 = rr0 + v1, rr2 = rr1 + v2, rr3 = rr2 + v3;
            rp[(size_t)(n + 0) * 256] = rr0; rtp[n + 0] = rr0;
            rp[(size_t)(n + 1) * 256] = rr1; rtp[n + 1] = rr1;
            rp[(size_t)(n + 2) * 256] = rr2; rtp[n + 2] = rr2;
            rp[(size_t)(n + 3) * 256] = rr3; rtp[n + 3] = rr3;
            run = rr3;
        }
    }
}

// ============ ONCE: logits + masked softmax; blocks >= R_: inline layer 0 ============
__global__ void softmax_once(const float* __restrict__ r, const float* __restrict__ rT,
                             const float* __restrict__ ck, const float* __restrict__ Wd1,
                             const int* __restrict__ code_length,
                             float* __restrict__ spT_mid, float* __restrict__ spT5,
                             const float* __restrict__ hw, const float* __restrict__ cz,
                             const float* __restrict__ init_a,
                             const float* __restrict__ Wh_e, const float* __restrict__ q,
                             float* __restrict__ ve, float* __restrict__ c1,
                             float* __restrict__ h1, float* __restrict__ p1) {
    __shared__ float ri[H_], ckl[H_], wd[H_];
    __shared__ float part[8][128];
    __shared__ float red[4];
    int t = threadIdx.x;             // 0..1023
    int bi = blockIdx.x;
    if (bi >= R_) {                  // ---- inline layer 0 for batch b ----
        int b = bi - R_;
        const float* q1 = q + (size_t)(b * N_ + 1) * 1024;
        if (t < 256) {
            float gi = q1[t] + hw[t];
            float gf = q1[256 + t] + hw[256 + t];
            float gg = q1[512 + t] + hw[512 + t];
            float go = q1[768 + t] + hw[768 + t];
            float cpr = sigm(gf) * init_a[t] + sigm(gi) * tanh_f(gg);
            float hpr = sigm(go) * tanh_f(cpr);
            float sc = __builtin_amdgcn_rcpf(1.0f + 1e-7f);   // w=1, wsum=1
            float hpv = hpr * sc;
            c1[(size_t)(b * N_ + 1) * 256 + t] = cpr * sc;
            h1[(size_t)(b * N_ + 1) * 256 + t] = hpv;
            ri[t] = hpv;
            if (t < N_) p1[b * N_ + t] = (t == 1) ? 1.0f : 0.0f;
        }
        __syncthreads();
        // ve1 row: all 1024 threads, col = t, 4-acc pipelined
        float a0 = 0.f, a1 = 0.f, a2 = 0.f, a3 = 0.f;
#pragma unroll 4
        for (int k = 0; k < 256; k += 4) {
            a0 = fmaf(ri[k + 0], Wh_e[(size_t)(k + 0) * 1024 + t], a0);
            a1 = fmaf(ri[k + 1], Wh_e[(size_t)(k + 1) * 1024 + t], a1);
            a2 = fmaf(ri[k + 2], Wh_e[(size_t)(k + 2) * 1024 + t], a2);
            a3 = fmaf(ri[k + 3], Wh_e[(size_t)(k + 3) * 1024 + t], a3);
        }
        ve[(size_t)(b * N_ + 1) * 1024 + t] = cz[t] - q1[t] + ((a0 + a1) + (a2 + a3));
        return;
    }
    int j = t & 127, half = t >> 7;
    int b = bi / N_, i = bi % N_;
    if (t < H_) {
        ri[t] = r[(size_t)bi * H_ + t];
        ckl[t] = ck[t];
        wd[t] = Wd1[256 + t];
    }
    __syncthreads();
    int len = code_length[b] / T_;
    bool valid = (j < N_) && ((j > i && j <= len) || (j == len));
    float acc = 0.0f;
    if (valid) {
        const float* rTb = rT + (size_t)b * H_ * 128 + j;
        int h0 = half * 32;
#pragma unroll 4
        for (int hh = 0; hh < 32; hh++) {
            int h = h0 + hh;
            float v = rTb[(size_t)h * 128] - ri[h] + ckl[h];
            acc = fmaf(fmaxf(v, 0.0f), wd[h], acc);
        }
    }
    part[half][j] = acc;
    __syncthreads();
    float logit = -3.0e38f;
    if (t < 128) {
        if (valid)
            logit = part[0][j] + part[1][j] + part[2][j] + part[3][j]
                  + part[4][j] + part[5][j] + part[6][j] + part[7][j];
        float m = logit;
#pragma unroll
        for (int off = 32; off; off >>= 1) m = fmaxf(m, __shfl_xor(m, off));
        if ((t & 63) == 0) red[t >> 6] = m;
    }
    __syncthreads();
    float e = 0.0f;
    if (t < 128) {
        float m = fmaxf(red[0], red[1]);
        e = valid ? __builtin_amdgcn_exp2f(1.44269504f * (logit - m)) : 0.0f;
        float s = e;
#pragma unroll
        for (int off = 32; off; off >>= 1) s += __shfl_xor(s, off);
        if ((t & 63) == 0) red[2 + (t >> 6)] = s;
    }
    __syncthreads();
    if (t < 128 && j < N_) {
        float s = red[2] + red[3];
        size_t o = ((size_t)b * N_ + j) * 128 + i;
        spT_mid[o] = e / s;
        spT5[o] = (j == len) ? 1.0f : 0.0f;
    }
}

// ============ fused aggregate + ve-matvec: 1024 thr, 4-way i-split ============
// ve[bj] = hn[bj] @ Wh_e + cz - q[bj] is row-local to this block -> computed in
// epilogue (hn row already in LDS). vout == nullptr for the final layer.
__global__ __launch_bounds__(1024) void aggregate(const float* __restrict__ q,
        const float* __restrict__ ve, const float* __restrict__ spT,
        const float* __restrict__ p, const float* __restrict__ cc,
        const float* __restrict__ hc, const float* __restrict__ Wh_e,
        const float* __restrict__ cz, float* __restrict__ cn,
        float* __restrict__ hn, float* __restrict__ pn, float* __restrict__ vout) {
    __shared__ float qj[1024];
    __shared__ float wcol[128];
    __shared__ int vlist[128];
    __shared__ int cnts[2];
    __shared__ float wsums[2];
    __shared__ float parts[4][2][H_];
    __shared__ float hrow[H_];
    int t = threadIdx.x;
    int bj = blockIdx.x;
    int b = bj / N_, j = bj - b * N_;
    bool pred = false;
    int rank = 0;
    if (t < 128) {                   // waves 0,1 fully active
        float wv = (t < N_) ? spT[(size_t)bj * 128 + t] * p[b * N_ + t] : 0.f;
        wcol[t] = wv;
        float s = wv;
#pragma unroll
        for (int off = 32; off; off >>= 1) s += __shfl_xor(s, off);
        pred = (wv != 0.0f);
        unsigned long long mask = __ballot(pred);
        int lane = t & 63;
        rank = __popcll(mask & ((1ull << lane) - 1ull));
        if (lane == 0) { cnts[t >> 6] = (int)__popcll(mask); wsums[t >> 6] = s; }
    }
    __syncthreads();
    float wsum = wsums[0] + wsums[1];
    int nv = cnts[0] + cnts[1];
    if (t < 128 && pred) vlist[(t >= 64 ? cnts[0] : 0) + rank] = t;
    if (wsum == 0.0f) {              // pn=0 -> ve row never read next layer
        if (t < 256) {
            cn[(size_t)bj * H_ + t] = 0.0f;
            hn[(size_t)bj * H_ + t] = 0.0f;
            if (t == 0) pn[bj] = 0.0f;
        }
        return;
    }
    qj[t] = q[(size_t)bj * 1024 + t];
    __syncthreads();                 // covers vlist writes and qj stage
    int hh = t & 255, vs = t >> 8;   // 4-way i-split
    float ac = 0.f, ah = 0.f;
    for (int v = vs; v < nv; v += 4) {
        int i = vlist[v];
        float wv = wcol[i];
        size_t rowi = (size_t)b * N_ + i;
        if (j > i) {
            const float* vei = ve + rowi * 1024;
            float gi = qj[hh] + vei[hh];
            float gf = qj[256 + hh] + vei[256 + hh];
            float gg = qj[512 + hh] + vei[512 + hh];
            float go = qj[768 + hh] + vei[768 + hh];
            float c2 = cc[rowi * H_ + hh];
            float cp = sigm(gf) * c2 + sigm(gi) * tanh_f(gg);
            float hp = sigm(go) * tanh_f(cp);
            ac = fmaf(wv, cp, ac);
            ah = fmaf(wv, hp, ah);
        } else {
            ac = fmaf(wv, cc[rowi * H_ + hh], ac);
            ah = fmaf(wv, hc[rowi * H_ + hh], ah);
        }
    }
    parts[vs][0][hh] = ac;
    parts[vs][1][hh] = ah;
    __syncthreads();
    if (t < 256) {
        float inv = __builtin_amdgcn_rcpf(wsum + 1e-7f);
        float cval = ((parts[0][0][t] + parts[1][0][t])
                    + (parts[2][0][t] + parts[3][0][t])) * inv;
        float hval = ((parts[0][1][t] + parts[1][1][t])
                    + (parts[2][1][t] + parts[3][1][t])) * inv;
        cn[(size_t)bj * H_ + t] = cval;
        hn[(size_t)bj * H_ + t] = hval;
        hrow[t] = hval;
        if (t == 0) pn[bj] = wsum;
    }
    if (!vout) return;
    __syncthreads();
    // ---- ve epilogue: col t = hrow @ Wh_e[:,t] + cz[t] - q[bj,t] ----
    float a0 = 0.f, a1 = 0.f, a2 = 0.f, a3 = 0.f;
    const float* wp = Wh_e + t;
#pragma unroll 4
    for (int k = 0; k < 256; k += 4) {
        a0 = fmaf(hrow[k + 0], wp[(size_t)(k + 0) * 1024], a0);
        a1 = fmaf(hrow[k + 1], wp[(size_t)(k + 1) * 1024], a1);
        a2 = fmaf(hrow[k + 2], wp[(size_t)(k + 2) * 1024], a2);
        a3 = fmaf(hrow[k + 3], wp[(size_t)(k + 3) * 1024], a3);
    }
    vout[(size_t)bj * 1024 + t] = cz[t] - qj[t] + ((a0 + a1) + (a2 + a3));
}

// ---------------- host launcher ----------------

extern "C" void kernel_launch(void* const* d_in, const int* in_sizes, int n_in,
                              void* d_out, int out_size, void* d_ws, size_t ws_size,
                              hipStream_t stream) {
    const int*   code_statements = (const int*)d_in[0];
    const int*   code_length = (const int*)d_in[1];
    const float* embed = (const float*)d_in[2];
    const float* Wx_s = (const float*)d_in[3];
    const float* Wh_s = (const float*)d_in[4];
    const float* b_s  = (const float*)d_in[5];
    const float* W_se = (const float*)d_in[6];
    const float* b_se = (const float*)d_in[7];
    const float* Wx_e = (const float*)d_in[8];
    const float* Wh_e = (const float*)d_in[9];
    const float* b_e  = (const float*)d_in[10];
    const float* W_sd = (const float*)d_in[13];
    const float* b_sd = (const float*)d_in[14];
    const float* W_d1 = (const float*)d_in[15];
    // d_in[11] W_hk, d_in[12] b_hk, d_in[16] b_d1: softmax-invariant -> unused
    const float* init_a = (const float*)d_in[17];
    const float* init_b = (const float*)d_in[18];
    float* out = (float*)d_out;

    float* wsf = (float*)d_ws;
    size_t off = 0;
    auto alloc = [&](size_t n) { float* p = wsf + off; off += n; return p; };
    float* cz = alloc(1024);
    float* ck = alloc(256);
    float* hw = alloc(1024);             // init_b@Wh_e + cz
    float* xz = alloc((size_t)3072 * 1024);
    float* stmt = alloc(384 * 256);      // LSTM h buffer
    float* Mbuf = alloc(256 * 1280);     // [M1 | M2]
    float* y2   = alloc((size_t)384 * 1280);  // stmt @ [M1 | M2]
    float* q  = alloc(R_ * 1024);
    float* r_ = alloc(R_ * 256);
    float* rT = alloc(4 * 256 * 128);
    float* ve = alloc(R_ * 1024);        // h@Wh_e + cz - q
    float* spT_mid = alloc(R_ * 128);
    float* spT5    = alloc(R_ * 128);
    float* p0 = alloc(R_);
    float* p1 = alloc(R_);
    float* c0 = alloc(R_ * 256);
    float* c1 = alloc(R_ * 256);
    float* h0 = alloc(R_ * 256);
    float* h1 = alloc(R_ * 256);

    // prologue: xz tiles + M1/M2 + cz/hw/ck
    prologue<<<dim3(429), 512, 0, stream>>>(code_statements, embed, Wx_s, b_s,
                                            b_se, Wx_e, b_e, W_sd, b_sd, Wh_e,
                                            W_se, init_b, xz, cz, ck, hw, Mbuf);
    // all 8 LSTM steps, one launch
    lstm_onepass<<<dim3(192), 1024, 0, stream>>>(xz, Wh_s, stmt);
    // y2 = stmt @ [M1|M2]  (cumsum/GEMM commuted by linearity)
    gemm_t<16><<<dim3(10, 24), 256, 0, stream>>>(stmt, Mbuf, y2, 384, 1280);
    // prefix-scan -> q, ve0, r_, rT
    scan_wide<<<dim3(20), 256, 0, stream>>>(y2, hw, q, ve, r_, rT);
    // softmax (layer-invariant) + inline layer 0 (4 extra blocks)
    softmax_once<<<dim3(R_ + B_), 1024, 0, stream>>>(r_, rT, ck, W_d1, code_length,
                                                     spT_mid, spT5, hw, cz, init_a,
                                                     Wh_e, q, ve, c1, h1, p1);

    // execution layers 1..5, each ONE fused dispatch (aggregate + ve epilogue)
    for (int layer = 1; layer < NL_; layer++) {
        bool odd = (layer & 1);
        float* pc = odd ? p1 : p0;
        float* pn = odd ? p0 : p1;
        float* cc = odd ? c1 : c0;
        float* cn = odd ? c0 : c1;
        float* hc = odd ? h1 : h0;
        float* hn = odd ? h0 : h1;
        if (layer == NL_ - 1) hn = out;  // final h straight to d_out
        const float* spT = (layer == NL_ - 1) ? spT5 : spT_mid;
        float* vout = (layer < NL_ - 1) ? ve : nullptr;
        aggregate<<<dim3(R_), 1024, 0, stream>>>(q, ve, spT, pc, cc, hc, Wh_e, cz,
                                                 cn, hn, pn, vout);
    }
}

// Round 11
// 330.816 us; speedup vs baseline: 1.0338x; 1.0338x over previous
//
#include <hip/hip_runtime.h>
#include <cstddef>

// Problem constants
#define B_   4
#define NS_  96
#define T_   8
#define H_   256
#define N_   97      // NS + 1
#define NL_  6       // NUM_LAYERS
#define R_   388     // B_ * N_

// fast gates: v_exp_f32 (2^x) + v_rcp_f32
__device__ __forceinline__ float sigm(float x) {
    return __builtin_amdgcn_rcpf(1.0f + __builtin_amdgcn_exp2f(-1.44269504f * x));
}
__device__ __forceinline__ float tanh_f(float x) {
    return 1.0f - 2.0f * __builtin_amdgcn_rcpf(1.0f + __builtin_amdgcn_exp2f(2.88539008f * x));
}

__device__ __forceinline__ void fma16(float4 a, float4 w0, float4 w1, float4 w2,
                                      float4 w3, float* acc) {
    acc[0] = fmaf(a.x, w0.x, acc[0]); acc[1] = fmaf(a.x, w0.y, acc[1]);
    acc[2] = fmaf(a.x, w0.z, acc[2]); acc[3] = fmaf(a.x, w0.w, acc[3]);
    acc[0] = fmaf(a.y, w1.x, acc[0]); acc[1] = fmaf(a.y, w1.y, acc[1]);
    acc[2] = fmaf(a.y, w1.z, acc[2]); acc[3] = fmaf(a.y, w1.w, acc[3]);
    acc[0] = fmaf(a.z, w2.x, acc[0]); acc[1] = fmaf(a.z, w2.y, acc[1]);
    acc[2] = fmaf(a.z, w2.z, acc[2]); acc[3] = fmaf(a.z, w2.w, acc[3]);
    acc[0] = fmaf(a.w, w3.x, acc[0]); acc[1] = fmaf(a.w, w3.y, acc[1]);
    acc[2] = fmaf(a.w, w3.z, acc[2]); acc[3] = fmaf(a.w, w3.w, acc[3]);
}

// ============ prologue: 512-thr blocks ============
// 0..383: xz tiles; 384..415: M1 = W_se@Wx_e; 416..423: M2 = W_se@W_sd;
// 424..425: cz; 426..427: hw; 428: ck.  Small sections use 4-acc pipelined k-loops.
__global__ __launch_bounds__(512, 4) void prologue(
        const int* __restrict__ ids, const float* __restrict__ embed,
        const float* __restrict__ Wx_s, const float* __restrict__ b_s,
        const float* __restrict__ b_se, const float* __restrict__ Wx_e,
        const float* __restrict__ b_e, const float* __restrict__ W_sd,
        const float* __restrict__ b_sd, const float* __restrict__ Wh_e,
        const float* __restrict__ W_se, const float* __restrict__ init_b,
        float* __restrict__ xz, float* __restrict__ cz, float* __restrict__ ck,
        float* __restrict__ hw, float* __restrict__ Mbuf) {
    int bid = blockIdx.x, t = threadIdx.x;
    if (bid < 384) {                      // xz = embed[ids] @ Wx_s + b_s, 64x128 tile
        __shared__ float As[64][260];
        __shared__ int ridx[64];
        int r0 = (bid >> 3) * 64, n0 = (bid & 7) * 128;
        if (t < 64) ridx[t] = ids[r0 + t];
        __syncthreads();
#pragma unroll
        for (int m = 0; m < 8; m++) {     // stage 64x256 (8 float4/thread)
            int L = m * 512 + t;
            int r = L >> 6, c4 = (L & 63) * 4;
            *(float4*)&As[r][c4] = *(const float4*)(embed + (size_t)ridx[r] * 256 + c4);
        }
        __syncthreads();
        int rg = t >> 5, cg = t & 31;     // 16 row-groups x 32 col-quads
        float acc[4][4] = {};
        const float* wp = Wx_s + n0 + 4 * cg;
#pragma unroll 4
        for (int kb = 0; kb < 64; kb++) {
            float4 w0 = *(const float4*)(wp + (size_t)(4 * kb + 0) * 1024);
            float4 w1 = *(const float4*)(wp + (size_t)(4 * kb + 1) * 1024);
            float4 w2 = *(const float4*)(wp + (size_t)(4 * kb + 2) * 1024);
            float4 w3 = *(const float4*)(wp + (size_t)(4 * kb + 3) * 1024);
#pragma unroll
            for (int i = 0; i < 4; i++) {
                float4 a = *(const float4*)&As[rg * 4 + i][4 * kb];
                fma16(a, w0, w1, w2, w3, acc[i]);
            }
        }
        int col = n0 + 4 * cg;
        float4 bv = *(const float4*)&b_s[col];
#pragma unroll
        for (int i = 0; i < 4; i++) {
            int r = r0 + rg * 4 + i;
            float4 o = make_float4(acc[i][0] + bv.x, acc[i][1] + bv.y,
                                   acc[i][2] + bv.z, acc[i][3] + bv.w);
            *(float4*)&xz[(size_t)r * 1024 + col] = o;
        }
    } else if (bid < 424) {               // M1 (32 blocks) / M2 (8 blocks)
        __shared__ float As[64][260];
        bool isM1 = bid < 416;
        int mb = isM1 ? bid - 384 : bid - 416;
        int r0m = isM1 ? (mb >> 3) * 64 : (mb >> 1) * 64;
        int n0 = isM1 ? (mb & 7) * 128 : (mb & 1) * 128;
        const float* W = isM1 ? Wx_e : W_sd;
        int NC = isM1 ? 1024 : 256;
        int cbase = isM1 ? 0 : 1024;
#pragma unroll
        for (int m = 0; m < 8; m++) {     // stage W_se rows r0m..r0m+63
            int L = m * 512 + t;
            int r = L >> 6, c4 = (L & 63) * 4;
            *(float4*)&As[r][c4] = *(const float4*)(W_se + (size_t)(r0m + r) * 256 + c4);
        }
        __syncthreads();
        int rg = t >> 5, cg = t & 31;
        float acc[4][4] = {};
        const float* wp = W + n0 + 4 * cg;
#pragma unroll 4
        for (int kb = 0; kb < 64; kb++) {
            float4 w0 = *(const float4*)(wp + (size_t)(4 * kb + 0) * NC);
            float4 w1 = *(const float4*)(wp + (size_t)(4 * kb + 1) * NC);
            float4 w2 = *(const float4*)(wp + (size_t)(4 * kb + 2) * NC);
            float4 w3 = *(const float4*)(wp + (size_t)(4 * kb + 3) * NC);
#pragma unroll
            for (int i = 0; i < 4; i++) {
                float4 a = *(const float4*)&As[rg * 4 + i][4 * kb];
                fma16(a, w0, w1, w2, w3, acc[i]);
            }
        }
        int col = cbase + n0 + 4 * cg;
#pragma unroll
        for (int i = 0; i < 4; i++) {
            int r = r0m + rg * 4 + i;
            *(float4*)&Mbuf[(size_t)r * 1280 + col] =
                make_float4(acc[i][0], acc[i][1], acc[i][2], acc[i][3]);
        }
    } else if (bid < 426) {               // cz[n] = b_e + b_se@Wx_e (pipelined)
        int n = (bid - 424) * 512 + t;
        float acc[4] = {};
#pragma unroll 4
        for (int k = 0; k < 256; k += 4) {
            acc[0] = fmaf(b_se[k + 0], Wx_e[(size_t)(k + 0) * 1024 + n], acc[0]);
            acc[1] = fmaf(b_se[k + 1], Wx_e[(size_t)(k + 1) * 1024 + n], acc[1]);
            acc[2] = fmaf(b_se[k + 2], Wx_e[(size_t)(k + 2) * 1024 + n], acc[2]);
            acc[3] = fmaf(b_se[k + 3], Wx_e[(size_t)(k + 3) * 1024 + n], acc[3]);
        }
        cz[n] = b_e[n] + ((acc[0] + acc[1]) + (acc[2] + acc[3]));
    } else if (bid < 428) {               // hw[n] = cz[n] + init_b@Wh_e (pipelined)
        int n = (bid - 426) * 512 + t;
        float acc[4] = {}, bcc[4] = {};
#pragma unroll 4
        for (int k = 0; k < 256; k += 4) {
            acc[0] = fmaf(b_se[k + 0], Wx_e[(size_t)(k + 0) * 1024 + n], acc[0]);
            acc[1] = fmaf(b_se[k + 1], Wx_e[(size_t)(k + 1) * 1024 + n], acc[1]);
            acc[2] = fmaf(b_se[k + 2], Wx_e[(size_t)(k + 2) * 1024 + n], acc[2]);
            acc[3] = fmaf(b_se[k + 3], Wx_e[(size_t)(k + 3) * 1024 + n], acc[3]);
            bcc[0] = fmaf(init_b[k + 0], Wh_e[(size_t)(k + 0) * 1024 + n], bcc[0]);
            bcc[1] = fmaf(init_b[k + 1], Wh_e[(size_t)(k + 1) * 1024 + n], bcc[1]);
            bcc[2] = fmaf(init_b[k + 2], Wh_e[(size_t)(k + 2) * 1024 + n], bcc[2]);
            bcc[3] = fmaf(init_b[k + 3], Wh_e[(size_t)(k + 3) * 1024 + n], bcc[3]);
        }
        hw[n] = b_e[n] + ((acc[0] + acc[1]) + (acc[2] + acc[3]))
                       + ((bcc[0] + bcc[1]) + (bcc[2] + bcc[3]));
    } else {                              // ck (pipelined)
        if (t < 256) {
            float acc[4] = {};
#pragma unroll 4
            for (int k = 0; k < 256; k += 4) {
                acc[0] = fmaf(b_se[k + 0], W_sd[(size_t)(k + 0) * 256 + t], acc[0]);
                acc[1] = fmaf(b_se[k + 1], W_sd[(size_t)(k + 1) * 256 + t], acc[1]);
                acc[2] = fmaf(b_se[k + 2], W_sd[(size_t)(k + 2) * 256 + t], acc[2]);
                acc[3] = fmaf(b_se[k + 3], W_sd[(size_t)(k + 3) * 256 + t], acc[3]);
            }
            ck[t] = b_sd[t] + ((acc[0] + acc[1]) + (acc[2] + acc[3]));
        }
    }
}

// ============ lstm_onepass v3: all 8 steps, one launch; S=2, 192 blocks ============
__global__ __launch_bounds__(1024) void lstm_onepass(const float* __restrict__ xz,
        const float* __restrict__ Wh, float* __restrict__ hbuf) {
    __shared__ float zpart[4][2][1024];   // 32 KB
    __shared__ float h_s[2][260];         // 2 KB
    __shared__ float Wh_c[28][1024];      // 112 KB cached rows 0..27
    int t = threadIdx.x;
    int s0 = blockIdx.x * 2;
    int kg = t >> 8, tg = t & 255;
    int sg = (t >> 8) & 1, cc = t & 255;
#pragma unroll
    for (int m = 0; m < 7; m++) {
        int L = m * 1024 + t;
        int r = L >> 8, c4 = (L & 255) * 4;
        *(float4*)&Wh_c[r][c4] = *(const float4*)(Wh + (size_t)r * 1024 + c4);
    }
    float creg = 0.0f, hreg = 0.0f;
    if (t < 512) {
        const float* z0 = xz + ((size_t)(s0 + sg) * T_) * 1024;
        float gi = z0[cc], gg = z0[512 + cc], go = z0[768 + cc];
        creg = sigm(gi) * tanh_f(gg);
        hreg = sigm(go) * tanh_f(creg);
        h_s[sg][cc] = hreg;
    }
    __syncthreads();
    for (int step = 1; step < T_; step++) {
        float x0 = 0.f, x1 = 0.f, x2 = 0.f, x3 = 0.f;
        if (t < 512) {
            const float* xzp = xz + ((size_t)(s0 + sg) * T_ + step) * 1024;
            x0 = xzp[cc]; x1 = xzp[256 + cc]; x2 = xzp[512 + cc]; x3 = xzp[768 + cc];
        }
        float4 z[2] = {};
        const float* wp = Wh + (size_t)(kg * 64) * 1024 + 4 * tg;
        int kbase = kg * 64;
        if (kg == 0) {
#pragma unroll
            for (int kb = 0; kb < 7; kb++) {
                float4 w0 = *(const float4*)&Wh_c[4 * kb + 0][4 * tg];
                float4 w1 = *(const float4*)&Wh_c[4 * kb + 1][4 * tg];
                float4 w2 = *(const float4*)&Wh_c[4 * kb + 2][4 * tg];
                float4 w3 = *(const float4*)&Wh_c[4 * kb + 3][4 * tg];
                int k = 4 * kb;
#pragma unroll
                for (int s = 0; s < 2; s++) {
                    float4 a = *(const float4*)&h_s[s][k];
                    fma16(a, w0, w1, w2, w3, (float*)&z[s]);
                }
            }
#pragma unroll 3
            for (int kb = 7; kb < 16; kb++) {
                float4 w0 = *(const float4*)(wp + (size_t)(4 * kb + 0) * 1024);
                float4 w1 = *(const float4*)(wp + (size_t)(4 * kb + 1) * 1024);
                float4 w2 = *(const float4*)(wp + (size_t)(4 * kb + 2) * 1024);
                float4 w3 = *(const float4*)(wp + (size_t)(4 * kb + 3) * 1024);
                int k = 4 * kb;
#pragma unroll
                for (int s = 0; s < 2; s++) {
                    float4 a = *(const float4*)&h_s[s][k];
                    fma16(a, w0, w1, w2, w3, (float*)&z[s]);
                }
            }
        } else {
#pragma unroll 4
            for (int kb = 0; kb < 16; kb++) {
                float4 w0 = *(const float4*)(wp + (size_t)(4 * kb + 0) * 1024);
                float4 w1 = *(const float4*)(wp + (size_t)(4 * kb + 1) * 1024);
                float4 w2 = *(const float4*)(wp + (size_t)(4 * kb + 2) * 1024);
                float4 w3 = *(const float4*)(wp + (size_t)(4 * kb + 3) * 1024);
                int k = kbase + 4 * kb;
#pragma unroll
                for (int s = 0; s < 2; s++) {
                    float4 a = *(const float4*)&h_s[s][k];
                    fma16(a, w0, w1, w2, w3, (float*)&z[s]);
                }
            }
        }
#pragma unroll
        for (int s = 0; s < 2; s++)
            *(float4*)&zpart[kg][s][4 * tg] = z[s];
        __syncthreads();
        if (t < 512) {
            float zv0 = x0 + zpart[0][sg][cc] + zpart[1][sg][cc]
                      + zpart[2][sg][cc] + zpart[3][sg][cc];
            float zv1 = x1 + zpart[0][sg][256 + cc] + zpart[1][sg][256 + cc]
                      + zpart[2][sg][256 + cc] + zpart[3][sg][256 + cc];
            float zv2 = x2 + zpart[0][sg][512 + cc] + zpart[1][sg][512 + cc]
                      + zpart[2][sg][512 + cc] + zpart[3][sg][512 + cc];
            float zv3 = x3 + zpart[0][sg][768 + cc] + zpart[1][sg][768 + cc]
                      + zpart[2][sg][768 + cc] + zpart[3][sg][768 + cc];
            creg = sigm(zv1) * creg + sigm(zv0) * tanh_f(zv2);
            hreg = sigm(zv3) * tanh_f(creg);
            h_s[sg][cc] = hreg;
        }
        __syncthreads();
    }
    if (t < 512) hbuf[(size_t)(s0 + sg) * H_ + cc] = hreg;
}

// ============ templated GEMM: C = A@W (+bias)(-subQ), p-gated rows, MT x 128 tile ============
template<int MT>
__global__ __launch_bounds__(256) void gemm_t(const float* __restrict__ A,
        const float* __restrict__ W, const float* __restrict__ bias,
        const float* __restrict__ subQ, const float* __restrict__ pgate,
        float* __restrict__ C, int R, int NC) {
    __shared__ float As[MT][260];
    __shared__ int anyflag;
    int t = threadIdx.x;
    int n0 = blockIdx.x * 128;
    int r0 = blockIdx.y * MT;
    if (pgate) {                          // skip blocks whose rows all have p == 0
        if (t == 0) anyflag = 0;
        __syncthreads();
        if (t < MT && r0 + t < R && pgate[r0 + t] != 0.0f) anyflag = 1;
        __syncthreads();
        if (!anyflag) return;
    }
#pragma unroll
    for (int m = 0; m < MT / 4; m++) {
        int L = m * 256 + t;
        int r = L >> 6, c4 = (L & 63) * 4;
        int rr = r0 + r;
        float4 v = make_float4(0.f, 0.f, 0.f, 0.f);
        if (rr < R) v = *(const float4*)(A + (size_t)rr * 256 + c4);
        *(float4*)&As[r][c4] = v;
    }
    __syncthreads();
    constexpr int RT = MT / 8;
    int rg = t >> 5, cg = t & 31;
    float acc[RT][4] = {};
    const float* wp = W + n0 + 4 * cg;
#pragma unroll 2
    for (int kb = 0; kb < 64; kb++) {
        float4 w0 = *(const float4*)(wp + (size_t)(4 * kb + 0) * NC);
        float4 w1 = *(const float4*)(wp + (size_t)(4 * kb + 1) * NC);
        float4 w2 = *(const float4*)(wp + (size_t)(4 * kb + 2) * NC);
        float4 w3 = *(const float4*)(wp + (size_t)(4 * kb + 3) * NC);
#pragma unroll
        for (int i = 0; i < RT; i++) {
            float4 a = *(const float4*)&As[rg * RT + i][4 * kb];
            fma16(a, w0, w1, w2, w3, acc[i]);
        }
    }
    int col = n0 + 4 * cg;
    float4 bv = make_float4(0.f, 0.f, 0.f, 0.f);
    if (bias) bv = *(const float4*)&bias[col];
#pragma unroll
    for (int i = 0; i < RT; i++) {
        int r = r0 + rg * RT + i;
        if (r < R) {
            float4 o = make_float4(acc[i][0] + bv.x, acc[i][1] + bv.y,
                                   acc[i][2] + bv.z, acc[i][3] + bv.w);
            if (subQ) {
                float4 s4 = *(const float4*)(subQ + (size_t)r * NC + col);
                o.x -= s4.x; o.y -= s4.y; o.z -= s4.z; o.w -= s4.w;
            }
            *(float4*)&C[(size_t)r * NC + col] = o;
        }
    }
}

// ============ scan_wide: per-batch column prefix scan of y2 -> q, ve0, r_, rT ============
// grid 20 = 4 batches x 5 chunks of 256 cols; 4-row batched loads break the
// dependent-load chain (chain is now only through 4 adds per group).
__global__ __launch_bounds__(256) void scan_wide(const float* __restrict__ y2,
        const float* __restrict__ hw, float* __restrict__ q, float* __restrict__ ve0,
        float* __restrict__ r_, float* __restrict__ rT) {
    int bid = blockIdx.x, t = threadIdx.x;
    int b = bid / 5, ch = bid - b * 5;
    int ccol = ch * 256 + t;
    const float* yp = y2 + (size_t)b * 96 * 1280 + ccol;
    if (ccol < 1024) {
        float hwv = hw[ccol];
        float* qp = q + (size_t)b * N_ * 1024 + ccol;
        float* vp = ve0 + (size_t)b * N_ * 1024 + ccol;
        qp[0] = 0.0f; vp[0] = hwv;        // row n=0: pref = 0
        float run = 0.0f;
#pragma unroll 2
        for (int n = 1; n < N_; n += 4) {
            float v0 = yp[(size_t)(n - 1) * 1280];
            float v1 = yp[(size_t)(n + 0) * 1280];
            float v2 = yp[(size_t)(n + 1) * 1280];
            float v3 = yp[(size_t)(n + 2) * 1280];
            float rr0 = run + v0, rr1 = rr0 + v1, rr2 = rr1 + v2, rr3 = rr2 + v3;
            qp[(size_t)(n + 0) * 1024] = rr0; vp[(size_t)(n + 0) * 1024] = hwv - rr0;
            qp[(size_t)(n + 1) * 1024] = rr1; vp[(size_t)(n + 1) * 1024] = hwv - rr1;
            qp[(size_t)(n + 2) * 1024] = rr2; vp[(size_t)(n + 2) * 1024] = hwv - rr2;
            qp[(size_t)(n + 3) * 1024] = rr3; vp[(size_t)(n + 3) * 1024] = hwv - rr3;
            run = rr3;
        }
    } else {
        int rc = ccol - 1024;
        float* rp = r_ + (size_t)b * N_ * 256 + rc;
        float* rtp = rT + ((size_t)b * 256 + rc) * 128;
        rp[0] = 0.0f; rtp[0] = 0.0f;
        float run = 0.0f;
#pragma unroll 2
        for (int n = 1; n < N_; n += 4) {
            float v0 = yp[(size_t)(n - 1) * 1280];
            float v1 = yp[(size_t)(n + 0) * 1280];
            float v2 = yp[(size_t)(n + 1) * 1280];
            float v3 = yp[(size_t)(n + 2) * 1280];
            float rr0 = run + v0, rr1 = rr0 + v1, rr2 = rr1 + v2, rr3 = rr2 + v3;
            rp[(size_t)(n + 0) * 256] = rr0; rtp[n + 0] = rr0;
            rp[(size_t)(n + 1) * 256] = rr1; rtp[n + 1] = rr1;
            rp[(size_t)(n + 2) * 256] = rr2; rtp[n + 2] = rr2;
            rp[(size_t)(n + 3) * 256] = rr3; rtp[n + 3] = rr3;
            run = rr3;
        }
    }
}

// ============ ONCE: logits + masked softmax; blocks >= R_: inline layer 0 ============
__global__ void softmax_once(const float* __restrict__ r, const float* __restrict__ rT,
                             const float* __restrict__ ck, const float* __restrict__ Wd1,
                             const int* __restrict__ code_length,
                             float* __restrict__ spT_mid, float* __restrict__ spT5,
                             const float* __restrict__ hw, const float* __restrict__ cz,
                             const float* __restrict__ init_a,
                             const float* __restrict__ Wh_e, const float* __restrict__ q,
                             float* __restrict__ ve, float* __restrict__ c1,
                             float* __restrict__ h1, float* __restrict__ p1) {
    __shared__ float ri[H_], ckl[H_], wd[H_];
    __shared__ float part[8][128];
    __shared__ float red[4];
    int t = threadIdx.x;             // 0..1023
    int bi = blockIdx.x;
    if (bi >= R_) {                  // ---- inline layer 0 for batch b ----
        int b = bi - R_;
        const float* q1 = q + (size_t)(b * N_ + 1) * 1024;
        if (t < 256) {
            float gi = q1[t] + hw[t];
            float gf = q1[256 + t] + hw[256 + t];
            float gg = q1[512 + t] + hw[512 + t];
            float go = q1[768 + t] + hw[768 + t];
            float cpr = sigm(gf) * init_a[t] + sigm(gi) * tanh_f(gg);
            float hpr = sigm(go) * tanh_f(cpr);
            float sc = __builtin_amdgcn_rcpf(1.0f + 1e-7f);   // w=1, wsum=1
            float hpv = hpr * sc;
            c1[(size_t)(b * N_ + 1) * 256 + t] = cpr * sc;
            h1[(size_t)(b * N_ + 1) * 256 + t] = hpv;
            ri[t] = hpv;
            if (t < N_) p1[b * N_ + t] = (t == 1) ? 1.0f : 0.0f;
        }
        __syncthreads();
        // ve1 row: all 1024 threads, col = t, 4-acc pipelined
        float a0 = 0.f, a1 = 0.f, a2 = 0.f, a3 = 0.f;
#pragma unroll 4
        for (int k = 0; k < 256; k += 4) {
            a0 = fmaf(ri[k + 0], Wh_e[(size_t)(k + 0) * 1024 + t], a0);
            a1 = fmaf(ri[k + 1], Wh_e[(size_t)(k + 1) * 1024 + t], a1);
            a2 = fmaf(ri[k + 2], Wh_e[(size_t)(k + 2) * 1024 + t], a2);
            a3 = fmaf(ri[k + 3], Wh_e[(size_t)(k + 3) * 1024 + t], a3);
        }
        ve[(size_t)(b * N_ + 1) * 1024 + t] = cz[t] - q1[t] + ((a0 + a1) + (a2 + a3));
        return;
    }
    int j = t & 127, half = t >> 7;
    int b = bi / N_, i = bi % N_;
    if (t < H_) {
        ri[t] = r[(size_t)bi * H_ + t];
        ckl[t] = ck[t];
        wd[t] = Wd1[256 + t];
    }
    __syncthreads();
    int len = code_length[b] / T_;
    bool valid = (j < N_) && ((j > i && j <= len) || (j == len));
    float acc = 0.0f;
    if (valid) {
        const float* rTb = rT + (size_t)b * H_ * 128 + j;
        int h0 = half * 32;
#pragma unroll 4
        for (int hh = 0; hh < 32; hh++) {
            int h = h0 + hh;
            float v = rTb[(size_t)h * 128] - ri[h] + ckl[h];
            acc = fmaf(fmaxf(v, 0.0f), wd[h], acc);
        }
    }
    part[half][j] = acc;
    __syncthreads();
    float logit = -3.0e38f;
    if (t < 128) {
        if (valid)
            logit = part[0][j] + part[1][j] + part[2][j] + part[3][j]
                  + part[4][j] + part[5][j] + part[6][j] + part[7][j];
        float m = logit;
#pragma unroll
        for (int off = 32; off; off >>= 1) m = fmaxf(m, __shfl_xor(m, off));
        if ((t & 63) == 0) red[t >> 6] = m;
    }
    __syncthreads();
    float e = 0.0f;
    if (t < 128) {
        float m = fmaxf(red[0], red[1]);
        e = valid ? __builtin_amdgcn_exp2f(1.44269504f * (logit - m)) : 0.0f;
        float s = e;
#pragma unroll
        for (int off = 32; off; off >>= 1) s += __shfl_xor(s, off);
        if ((t & 63) == 0) red[2 + (t >> 6)] = s;
    }
    __syncthreads();
    if (t < 128 && j < N_) {
        float s = red[2] + red[3];
        size_t o = ((size_t)b * N_ + j) * 128 + i;
        spT_mid[o] = e / s;
        spT5[o] = (j == len) ? 1.0f : 0.0f;
    }
}

// ============ per-layer aggregate: 1024 thr, 4-way i-split ============
__global__ __launch_bounds__(1024) void aggregate(const float* __restrict__ q,
        const float* __restrict__ ve, const float* __restrict__ spT,
        const float* __restrict__ p, const float* __restrict__ cc,
        const float* __restrict__ hc, float* __restrict__ cn,
        float* __restrict__ hn, float* __restrict__ pn) {
    __shared__ float qj[1024];
    __shared__ float wcol[128];
    __shared__ int vlist[128];
    __shared__ int cnts[2];
    __shared__ float wsums[2];
    __shared__ float parts[4][2][H_];
    int t = threadIdx.x;
    int bj = blockIdx.x;
    int b = bj / N_, j = bj - b * N_;
    bool pred = false;
    int rank = 0;
    if (t < 128) {                   // waves 0,1 fully active
        float wv = (t < N_) ? spT[(size_t)bj * 128 + t] * p[b * N_ + t] : 0.f;
        wcol[t] = wv;
        float s = wv;
#pragma unroll
        for (int off = 32; off; off >>= 1) s += __shfl_xor(s, off);
        pred = (wv != 0.0f);
        unsigned long long mask = __ballot(pred);
        int lane = t & 63;
        rank = __popcll(mask & ((1ull << lane) - 1ull));
        if (lane == 0) { cnts[t >> 6] = (int)__popcll(mask); wsums[t >> 6] = s; }
    }
    __syncthreads();
    float wsum = wsums[0] + wsums[1];
    int nv = cnts[0] + cnts[1];
    if (t < 128 && pred) vlist[(t >= 64 ? cnts[0] : 0) + rank] = t;
    if (wsum == 0.0f) {
        if (t < 256) {
            cn[(size_t)bj * H_ + t] = 0.0f;
            hn[(size_t)bj * H_ + t] = 0.0f;
            if (t == 0) pn[bj] = 0.0f;
        }
        return;
    }
    qj[t] = q[(size_t)bj * 1024 + t];
    __syncthreads();                 // covers vlist writes and qj stage
    int hh = t & 255, vs = t >> 8;   // 4-way i-split
    float ac = 0.f, ah = 0.f;
    for (int v = vs; v < nv; v += 4) {
        int i = vlist[v];
        float wv = wcol[i];
        size_t rowi = (size_t)b * N_ + i;
        if (j > i) {
            const float* vei = ve + rowi * 1024;
            float gi = qj[hh] + vei[hh];
            float gf = qj[256 + hh] + vei[256 + hh];
            float gg = qj[512 + hh] + vei[512 + hh];
            float go = qj[768 + hh] + vei[768 + hh];
            float c2 = cc[rowi * H_ + hh];
            float cp = sigm(gf) * c2 + sigm(gi) * tanh_f(gg);
            float hp = sigm(go) * tanh_f(cp);
            ac = fmaf(wv, cp, ac);
            ah = fmaf(wv, hp, ah);
        } else {
            ac = fmaf(wv, cc[rowi * H_ + hh], ac);
            ah = fmaf(wv, hc[rowi * H_ + hh], ah);
        }
    }
    parts[vs][0][hh] = ac;
    parts[vs][1][hh] = ah;
    __syncthreads();
    if (t < 256) {
        float inv = __builtin_amdgcn_rcpf(wsum + 1e-7f);
        cn[(size_t)bj * H_ + t] = ((parts[0][0][t] + parts[1][0][t])
                                 + (parts[2][0][t] + parts[3][0][t])) * inv;
        hn[(size_t)bj * H_ + t] = ((parts[0][1][t] + parts[1][1][t])
                                 + (parts[2][1][t] + parts[3][1][t])) * inv;
        if (t == 0) pn[bj] = wsum;
    }
}

// ---------------- host launcher ----------------

extern "C" void kernel_launch(void* const* d_in, const int* in_sizes, int n_in,
                              void* d_out, int out_size, void* d_ws, size_t ws_size,
                              hipStream_t stream) {
    const int*   code_statements = (const int*)d_in[0];
    const int*   code_length = (const int*)d_in[1];
    const float* embed = (const float*)d_in[2];
    const float* Wx_s = (const float*)d_in[3];
    const float* Wh_s = (const float*)d_in[4];
    const float* b_s  = (const float*)d_in[5];
    const float* W_se = (const float*)d_in[6];
    const float* b_se = (const float*)d_in[7];
    const float* Wx_e = (const float*)d_in[8];
    const float* Wh_e = (const float*)d_in[9];
    const float* b_e  = (const float*)d_in[10];
    const float* W_sd = (const float*)d_in[13];
    const float* b_sd = (const float*)d_in[14];
    const float* W_d1 = (const float*)d_in[15];
    // d_in[11] W_hk, d_in[12] b_hk, d_in[16] b_d1: softmax-invariant -> unused
    const float* init_a = (const float*)d_in[17];
    const float* init_b = (const float*)d_in[18];
    float* out = (float*)d_out;

    float* wsf = (float*)d_ws;
    size_t off = 0;
    auto alloc = [&](size_t n) { float* p = wsf + off; off += n; return p; };
    float* cz = alloc(1024);
    float* ck = alloc(256);
    float* hw = alloc(1024);             // init_b@Wh_e + cz
    float* xz = alloc((size_t)3072 * 1024);
    float* stmt = alloc(384 * 256);      // LSTM h buffer
    float* Mbuf = alloc(256 * 1280);     // [M1 | M2]
    float* y2   = alloc((size_t)384 * 1280);  // stmt @ [M1 | M2]
    float* q  = alloc(R_ * 1024);
    float* r_ = alloc(R_ * 256);
    float* rT = alloc(4 * 256 * 128);
    float* ve = alloc(R_ * 1024);        // h@Wh_e + cz - q
    float* spT_mid = alloc(R_ * 128);
    float* spT5    = alloc(R_ * 128);
    float* p0 = alloc(R_);
    float* p1 = alloc(R_);
    float* c0 = alloc(R_ * 256);
    float* c1 = alloc(R_ * 256);
    float* h0 = alloc(R_ * 256);
    float* h1 = alloc(R_ * 256);

    // prologue: xz tiles + M1/M2 + cz/hw/ck
    prologue<<<dim3(429), 512, 0, stream>>>(code_statements, embed, Wx_s, b_s,
                                            b_se, Wx_e, b_e, W_sd, b_sd, Wh_e,
                                            W_se, init_b, xz, cz, ck, hw, Mbuf);
    // all 8 LSTM steps, one launch
    lstm_onepass<<<dim3(192), 1024, 0, stream>>>(xz, Wh_s, stmt);
    // y2 = stmt @ [M1|M2]  (cumsum/GEMM commuted by linearity)
    gemm_t<16><<<dim3(10, 24), 256, 0, stream>>>(stmt, Mbuf, nullptr, nullptr, nullptr,
                                                 y2, 384, 1280);
    // prefix-scan -> q, ve0, r_, rT
    scan_wide<<<dim3(20), 256, 0, stream>>>(y2, hw, q, ve, r_, rT);
    // softmax (layer-invariant) + inline layer 0 (4 extra blocks)
    softmax_once<<<dim3(R_ + B_), 1024, 0, stream>>>(r_, rT, ck, W_d1, code_length,
                                                     spT_mid, spT5, hw, cz, init_a,
                                                     Wh_e, q, ve, c1, h1, p1);

    // execution layers 1..5 (layer 0 inlined above; ve row for layer 1 ready)
    for (int layer = 1; layer < NL_; layer++) {
        bool odd = (layer & 1);
        float* pc = odd ? p1 : p0;
        float* pn = odd ? p0 : p1;
        float* cc = odd ? c1 : c0;
        float* cn = odd ? c0 : c1;
        float* hc = odd ? h1 : h0;
        float* hn = odd ? h0 : h1;
        if (layer == NL_ - 1) hn = out;  // final h straight to d_out
        const float* spT = (layer == NL_ - 1) ? spT5 : spT_mid;
        aggregate<<<dim3(R_), 1024, 0, stream>>>(q, ve, spT, pc, cc, hc, cn, hn, pn);
        if (layer < NL_ - 1)
            gemm_t<16><<<dim3(8, 25), 256, 0, stream>>>(hn, Wh_e, cz, q, pn,
                                                        ve, R_, 1024);
    }
}